// Round 4
// baseline (552.901 us; speedup 1.0000x reference)
//
#include <hip/hip_runtime.h>
#include <hip/hip_bf16.h>
#include <stdint.h>

typedef __bf16 bf16x8 __attribute__((ext_vector_type(8)));
typedef __bf16 bf16x4 __attribute__((ext_vector_type(4)));
typedef float f32x4 __attribute__((ext_vector_type(4)));

#define B_ 2
#define LQ_ 2048
#define LK_ 2048
#define NH_ 16
#define DH_ 64
#define DM_ 1024
#define NKT_ (LK_ / 64)

#define AS1 __attribute__((address_space(1)))
#define AS3 __attribute__((address_space(3)))

// async global->LDS, 16B/lane; LDS dest = uniform base + lane*16.
__device__ __forceinline__ void gload_lds16(const void* g, void* l) {
  __builtin_amdgcn_global_load_lds((const AS1 uint32_t*)g, (AS3 uint32_t*)l, 16, 0, 0);
}

// Pack mask (B,LQ,LK) int32 -> bitmask (1 bit/elem).
__global__ __launch_bounds__(256) void pack_mask_kernel(
    const int* __restrict__ m, unsigned* __restrict__ out) {
  int gtid = blockIdx.x * 256 + threadIdx.x;
  unsigned long long bal = __ballot(m[gtid] != 0);
  if ((threadIdx.x & 31) == 0)
    out[gtid >> 5] = (unsigned)(bal >> ((threadIdx.x & 32) ? 32 : 0));
}

// One kernel converting q,k,v (4.19M ea) and Wq,Wk,Wv (1.05M ea) fp32->bf16.
__global__ __launch_bounds__(256) void cvt6_kernel(
    const float* __restrict__ q, const float* __restrict__ k,
    const float* __restrict__ v, const float* __restrict__ wq,
    const float* __restrict__ wk, const float* __restrict__ wv,
    __bf16* __restrict__ X0, __bf16* __restrict__ X1, __bf16* __restrict__ X2,
    __bf16* __restrict__ W0, __bf16* __restrict__ W1, __bf16* __restrict__ W2) {
  int seg = blockIdx.y;
  if (seg >= 3 && blockIdx.x >= DM_ * DM_ / 1024) return;
  const float* s = seg == 0 ? q : seg == 1 ? k : seg == 2 ? v
                  : seg == 3 ? wq : seg == 4 ? wk : wv;
  __bf16* d = seg == 0 ? X0 : seg == 1 ? X1 : seg == 2 ? X2
             : seg == 3 ? W0 : seg == 4 ? W1 : W2;
  size_t t = (size_t)blockIdx.x * 256 + threadIdx.x;
  float4 f = ((const float4*)s)[t];
  bf16x4 o;
  o[0] = (__bf16)f.x; o[1] = (__bf16)f.y; o[2] = (__bf16)f.z; o[3] = (__bf16)f.w;
  ((bf16x4*)d)[t] = o;
}

// m97-style GEMM: C = X @ W^T + bias, 128x128 tile, BK=32, LDS-staged bf16.
// mode = blockIdx.z: 0=q (std only), 1=k (std + tiled-T), 2=v (tiled-T only).
// Tiled-T layout: T[bh][kti][d(64)][kl(64)].
__global__ __launch_bounds__(256) void proj_kernel(
    const __bf16* __restrict__ X0, const __bf16* __restrict__ X1,
    const __bf16* __restrict__ X2,
    const float* __restrict__ b0p, const float* __restrict__ b1p,
    const float* __restrict__ b2p,
    const __bf16* __restrict__ W0, const __bf16* __restrict__ W1,
    const __bf16* __restrict__ W2,
    __bf16* __restrict__ qh, __bf16* __restrict__ kh,
    __bf16* __restrict__ khT, __bf16* __restrict__ vhT) {
  __shared__ __align__(16) __bf16 abuf[128 * 32];
  __shared__ __align__(16) __bf16 bbuf[128 * 32];
  __shared__ __align__(16) __bf16 cbuf[128 * 72];  // std pass; tr pass uses [64][136]

  const int mode = blockIdx.z;
  const __bf16* X = mode == 0 ? X0 : (mode == 1 ? X1 : X2);
  const __bf16* W = mode == 0 ? W0 : (mode == 1 ? W1 : W2);
  const float* bias = mode == 0 ? b0p : (mode == 1 ? b1p : b2p);
  __bf16* ostd = mode == 0 ? qh : (mode == 1 ? kh : nullptr);
  __bf16* otr = mode == 0 ? nullptr : (mode == 1 ? khT : vhT);

  const int t = threadIdx.x;
  const int wave = t >> 6, lane = t & 63;
  const int lo16 = lane & 15, quad = lane >> 4;
  const int wm = wave >> 1, wn = wave & 1;
  const int m0 = blockIdx.x * 128, n0 = blockIdx.y * 128;
  const int srow = lane >> 2, scg = (lane & 3) ^ (srow & 3);  // XOR chunk swizzle

  f32x4 acc[4][4] = {};

  for (int k0 = 0; k0 < DM_; k0 += 32) {
    __syncthreads();
#pragma unroll
    for (int ii = 2 * wave; ii < 2 * wave + 2; ii++) {
      int row = ii * 16 + srow;
      gload_lds16(X + (size_t)(m0 + row) * DM_ + k0 + scg * 8, abuf + ii * 512);
      gload_lds16(W + (size_t)(n0 + row) * DM_ + k0 + scg * 8, bbuf + ii * 512);
    }
    __syncthreads();
    bf16x8 af[4], bfr[4];
#pragma unroll
    for (int g = 0; g < 4; g++) {
      int ar = wm * 64 + g * 16 + lo16;
      af[g] = *(const bf16x8*)(abuf + ar * 32 + (quad ^ (ar & 3)) * 8);
      int br = wn * 64 + g * 16 + lo16;
      bfr[g] = *(const bf16x8*)(bbuf + br * 32 + (quad ^ (br & 3)) * 8);
    }
#pragma unroll
    for (int gm = 0; gm < 4; gm++)
#pragma unroll
      for (int gn = 0; gn < 4; gn++)
        acc[gm][gn] =
            __builtin_amdgcn_mfma_f32_16x16x32_bf16(af[gm], bfr[gn], acc[gm][gn], 0, 0, 0);
  }

  const int b = m0 >> 11, l0 = m0 & 2047;
  for (int nhf = 0; nhf < 2; nhf++) {
    int h = (n0 >> 6) + nhf;
    int bh = b * NH_ + h;
    if (ostd) {
      __syncthreads();
      if (wn == nhf) {
#pragma unroll
        for (int gn = 0; gn < 4; gn++) {
          float bi = bias[n0 + nhf * 64 + gn * 16 + lo16];
#pragma unroll
          for (int gm = 0; gm < 4; gm++)
#pragma unroll
            for (int r = 0; r < 4; r++)
              cbuf[(wm * 64 + gm * 16 + quad * 4 + r) * 72 + gn * 16 + lo16] =
                  (__bf16)(acc[gm][gn][r] + bi);
        }
      }
      __syncthreads();
      int m = t >> 1, coff = (t & 1) * 32;
      __bf16* dst = ostd + ((size_t)bh * LQ_ + l0 + m) * DH_ + coff;
#pragma unroll
      for (int j = 0; j < 4; j++)
        *(bf16x8*)(dst + j * 8) = *(const bf16x8*)&cbuf[m * 72 + coff + j * 8];
    }
    if (otr) {
      __syncthreads();
      if (wn == nhf) {
#pragma unroll
        for (int gn = 0; gn < 4; gn++) {
          float bi = bias[n0 + nhf * 64 + gn * 16 + lo16];
#pragma unroll
          for (int gm = 0; gm < 4; gm++) {
            bf16x4 pk;
#pragma unroll
            for (int r = 0; r < 4; r++) pk[r] = (__bf16)(acc[gm][gn][r] + bi);
            *(bf16x4*)&cbuf[(gn * 16 + lo16) * 136 + wm * 64 + gm * 16 + quad * 4] = pk;
          }
        }
      }
      __syncthreads();
      int d = t >> 2, mc = (t & 3) * 32;
      int kti = (l0 + mc) >> 6, kl = (l0 + mc) & 63;
      __bf16* dst = otr + ((size_t)(bh * NKT_ + kti) * 64 + d) * 64 + kl;
#pragma unroll
      for (int j = 0; j < 4; j++)
        *(bf16x8*)(dst + j * 8) = *(const bf16x8*)&cbuf[d * 136 + mc + j * 8];
    }
  }
}

// Flash attention, NO k-loop barriers: all fragment loads are direct from
// global with fully-coalesced patterns (kh natural [bh][l][64]; khT/vhT in
// k-tiled [bh][kti][d][64] so every wave-group read is one contiguous 2KB
// span). p_lds is wave-private -> no __syncthreads; compiler pipelines
// next-tile loads behind MFMA/exp. XCD locality: blockIdx.x = bh.
__global__ __launch_bounds__(256) void attn_kernel(
    const __bf16* __restrict__ qh, const __bf16* __restrict__ kh,
    const __bf16* __restrict__ khT, const __bf16* __restrict__ vhT,
    const unsigned* __restrict__ maskp,
    float* __restrict__ out_k, float* __restrict__ out_v) {
  __shared__ __align__(16) __bf16 p_lds[4][16][72];

  const int t = threadIdx.x;
  const int wave = t >> 6, lane = t & 63;
  const int lo16 = lane & 15, quad = lane >> 4;
  const int bh = blockIdx.x;
  const int b = bh >> 4, h = bh & 15;
  const int q0 = blockIdx.y * 64 + wave * 16;

  const __bf16* qrow = qh + ((size_t)bh * LQ_ + q0 + lo16) * DH_ + quad * 8;
  bf16x8 a_q0 = *(const bf16x8*)(qrow);
  bf16x8 a_q1 = *(const bf16x8*)(qrow + 32);

  f32x4 acc_v[4] = {};
  f32x4 acc_k[4] = {};
  float lsum[4] = {0.f, 0.f, 0.f, 0.f};

  const __bf16* khb = kh + (size_t)bh * LK_ * DH_;
  const __bf16* ktb = khT + (size_t)bh * LK_ * DH_;
  const __bf16* vtb = vhT + (size_t)bh * LK_ * DH_;
  const unsigned* mb = maskp + ((size_t)b * LQ_ + q0 + quad * 4) * (LK_ / 32);
  const int voff = lo16 * 64 + quad * 8;  // identical frag offset for all 3 bufs

  for (int kti = 0; kti < NKT_; kti++) {
    const int tb = kti * 4096;
    // ---- S = Q K^T ----
    f32x4 s[4];
#pragma unroll
    for (int g = 0; g < 4; g++) {
      const __bf16* p = khb + tb + g * 1024 + voff;
      bf16x8 kb0 = *(const bf16x8*)(p);
      bf16x8 kb1 = *(const bf16x8*)(p + 32);
      f32x4 z = {};
      z = __builtin_amdgcn_mfma_f32_16x16x32_bf16(a_q0, kb0, z, 0, 0, 0);
      z = __builtin_amdgcn_mfma_f32_16x16x32_bf16(a_q1, kb1, z, 0, 0, 0);
      s[g] = z;
    }
    // ---- mask + exp (fixed max = 0) ----
    unsigned mw0[4], mw1[4];
#pragma unroll
    for (int r = 0; r < 4; r++) {
      mw0[r] = mb[r * (LK_ / 32) + kti * 2];
      mw1[r] = mb[r * (LK_ / 32) + kti * 2 + 1];
    }
#pragma unroll
    for (int g = 0; g < 4; g++) {
      int bitpos = (g * 16 + lo16) & 31;
#pragma unroll
      for (int r = 0; r < 4; r++) {
        unsigned w = (g >= 2) ? mw1[r] : mw0[r];
        float arg = ((w >> bitpos) & 1) ? s[g][r] * 0.125f : -28.0f;
        float p = __expf(arg);
        s[g][r] = p;
        lsum[r] += p;
      }
    }
    // ---- P: C-layout regs -> LDS -> A-layout frags (wave-private) ----
#pragma unroll
    for (int g = 0; g < 4; g++) {
#pragma unroll
      for (int r = 0; r < 4; r++)
        p_lds[wave][quad * 4 + r][g * 16 + lo16] = (__bf16)s[g][r];
    }
    bf16x8 a_p0 = *(const bf16x8*)&p_lds[wave][lo16][quad * 8];
    bf16x8 a_p1 = *(const bf16x8*)&p_lds[wave][lo16][32 + quad * 8];
    // ---- O_v += P V, O_k += P K ----
#pragma unroll
    for (int g = 0; g < 4; g++) {
      const __bf16* pv = vtb + tb + g * 1024 + voff;
      bf16x8 bv0 = *(const bf16x8*)(pv);
      bf16x8 bv1 = *(const bf16x8*)(pv + 32);
      acc_v[g] = __builtin_amdgcn_mfma_f32_16x16x32_bf16(a_p0, bv0, acc_v[g], 0, 0, 0);
      acc_v[g] = __builtin_amdgcn_mfma_f32_16x16x32_bf16(a_p1, bv1, acc_v[g], 0, 0, 0);
      const __bf16* pk = ktb + tb + g * 1024 + voff;
      bf16x8 bk0 = *(const bf16x8*)(pk);
      bf16x8 bk1 = *(const bf16x8*)(pk + 32);
      acc_k[g] = __builtin_amdgcn_mfma_f32_16x16x32_bf16(a_p0, bk0, acc_k[g], 0, 0, 0);
      acc_k[g] = __builtin_amdgcn_mfma_f32_16x16x32_bf16(a_p1, bk1, acc_k[g], 0, 0, 0);
    }
  }

#pragma unroll
  for (int off = 1; off < 16; off <<= 1) {
#pragma unroll
    for (int r = 0; r < 4; r++) lsum[r] += __shfl_xor(lsum[r], off, 64);
  }
  float inv_l[4];
#pragma unroll
  for (int r = 0; r < 4; r++) inv_l[r] = 1.0f / lsum[r];

  size_t obase = ((size_t)b * LQ_ + q0 + quad * 4) * DM_ + h * DH_;
#pragma unroll
  for (int g = 0; g < 4; g++) {
#pragma unroll
    for (int r = 0; r < 4; r++) {
      size_t idx = obase + (size_t)r * DM_ + g * 16 + lo16;
      out_k[idx] = acc_k[g][r] * inv_l[r];
      out_v[idx] = acc_v[g][r] * inv_l[r];
    }
  }
}

extern "C" void kernel_launch(void* const* d_in, const int* in_sizes, int n_in,
                              void* d_out, int out_size, void* d_ws, size_t ws_size,
                              hipStream_t stream) {
  const float* q = (const float*)d_in[0];
  const float* k = (const float*)d_in[1];
  const float* v = (const float*)d_in[2];
  const int* mask = (const int*)d_in[3];
  const float* Wq = (const float*)d_in[4];
  const float* bq = (const float*)d_in[5];
  const float* Wk = (const float*)d_in[6];
  const float* bk = (const float*)d_in[7];
  const float* Wv = (const float*)d_in[8];
  const float* bv = (const float*)d_in[9];
  float* out = (float*)d_out;

  // ws: qh | kh | khTt | vhTt (bf16, 8.4MB ea) | maskp (1MB)  -> ~34.6 MB
  const size_t HTOT = (size_t)B_ * NH_ * LQ_ * DH_;
  const size_t XTOT = (size_t)B_ * LQ_ * DM_;
  __bf16* qh = (__bf16*)d_ws;
  __bf16* kh = qh + HTOT;
  __bf16* khT = kh + HTOT;
  __bf16* vhT = khT + HTOT;
  unsigned* maskp = (unsigned*)(vhT + HTOT);

  // bf16 X/W scratch lives in d_out (dead before attn writes the outputs):
  // 3*8.4 + 3*2.1 = 31.5 MB << 67 MB output buffer.
  __bf16* X0 = (__bf16*)d_out;
  __bf16* X1 = X0 + XTOT;
  __bf16* X2 = X1 + XTOT;
  __bf16* W0 = X2 + XTOT;
  __bf16* W1 = W0 + (size_t)DM_ * DM_;
  __bf16* W2 = W1 + (size_t)DM_ * DM_;

  pack_mask_kernel<<<(B_ * LQ_ * LK_) / 256, 256, 0, stream>>>(mask, maskp);
  cvt6_kernel<<<dim3(XTOT / 1024, 6), 256, 0, stream>>>(
      q, k, v, Wq, Wk, Wv, X0, X1, X2, W0, W1, W2);
  proj_kernel<<<dim3(32, 8, 3), 256, 0, stream>>>(
      X0, X1, X2, bq, bk, bv, W0, W1, W2, qh, kh, khT, vhT);
  attn_kernel<<<dim3(32, 32), 256, 0, stream>>>(qh, kh, khT, vhT, maskp,
                                                out, out + (size_t)B_ * LQ_ * DM_);
}

// Round 5
// 291.841 us; speedup vs baseline: 1.8945x; 1.8945x over previous
//
#include <hip/hip_runtime.h>
#include <hip/hip_bf16.h>
#include <stdint.h>

typedef __bf16 bf16x8 __attribute__((ext_vector_type(8)));
typedef __bf16 bf16x4 __attribute__((ext_vector_type(4)));
typedef float f32x4 __attribute__((ext_vector_type(4)));

#define B_ 2
#define LQ_ 2048
#define LK_ 2048
#define NH_ 16
#define DH_ 64
#define DM_ 1024
#define NKT_ (LK_ / 64)

#define AS1 __attribute__((address_space(1)))
#define AS3 __attribute__((address_space(3)))

// async global->LDS, 16B/lane; LDS dest = uniform base + lane*16.
__device__ __forceinline__ void gload_lds16(const void* g, void* l) {
  __builtin_amdgcn_global_load_lds((const AS1 uint32_t*)g, (AS3 uint32_t*)l, 16, 0, 0);
}

// Pack mask (B,LQ,LK) int32 -> bitmask (1 bit/elem).
__global__ __launch_bounds__(256) void pack_mask_kernel(
    const int* __restrict__ m, unsigned* __restrict__ out) {
  int gtid = blockIdx.x * 256 + threadIdx.x;
  unsigned long long bal = __ballot(m[gtid] != 0);
  if ((threadIdx.x & 31) == 0)
    out[gtid >> 5] = (unsigned)(bal >> ((threadIdx.x & 32) ? 32 : 0));
}

// One kernel converting q,k,v (4.19M ea) and Wq,Wk,Wv (1.05M ea) fp32->bf16.
__global__ __launch_bounds__(256) void cvt6_kernel(
    const float* __restrict__ q, const float* __restrict__ k,
    const float* __restrict__ v, const float* __restrict__ wq,
    const float* __restrict__ wk, const float* __restrict__ wv,
    __bf16* __restrict__ X0, __bf16* __restrict__ X1, __bf16* __restrict__ X2,
    __bf16* __restrict__ W0, __bf16* __restrict__ W1, __bf16* __restrict__ W2) {
  int seg = blockIdx.y;
  if (seg >= 3 && blockIdx.x >= DM_ * DM_ / 1024) return;
  const float* s = seg == 0 ? q : seg == 1 ? k : seg == 2 ? v
                  : seg == 3 ? wq : seg == 4 ? wk : wv;
  __bf16* d = seg == 0 ? X0 : seg == 1 ? X1 : seg == 2 ? X2
             : seg == 3 ? W0 : seg == 4 ? W1 : W2;
  size_t t = (size_t)blockIdx.x * 256 + threadIdx.x;
  float4 f = ((const float4*)s)[t];
  bf16x4 o;
  o[0] = (__bf16)f.x; o[1] = (__bf16)f.y; o[2] = (__bf16)f.z; o[3] = (__bf16)f.w;
  ((bf16x4*)d)[t] = o;
}

// m97-style GEMM: C = X @ W^T + bias, 128x128 tile, BK=32, LDS-staged bf16.
// mode = blockIdx.z: 0=q (std only), 1=k (std + tiled-T), 2=v (tiled-T only).
// Tiled-T layout: T[bh][kti][d(64)][kl(64)].
__global__ __launch_bounds__(256) void proj_kernel(
    const __bf16* __restrict__ X0, const __bf16* __restrict__ X1,
    const __bf16* __restrict__ X2,
    const float* __restrict__ b0p, const float* __restrict__ b1p,
    const float* __restrict__ b2p,
    const __bf16* __restrict__ W0, const __bf16* __restrict__ W1,
    const __bf16* __restrict__ W2,
    __bf16* __restrict__ qh, __bf16* __restrict__ kh,
    __bf16* __restrict__ khT, __bf16* __restrict__ vhT) {
  // union: abuf/bbuf (16 KB) live in K-loop; cbuf (18 KB) only in epilogue.
  __shared__ __align__(16) __bf16 smem[128 * 72];
  __bf16* abuf = smem;
  __bf16* bbuf = smem + 128 * 32;
  __bf16* cbuf = smem;

  const int mode = blockIdx.z;
  const __bf16* X = mode == 0 ? X0 : (mode == 1 ? X1 : X2);
  const __bf16* W = mode == 0 ? W0 : (mode == 1 ? W1 : W2);
  const float* bias = mode == 0 ? b0p : (mode == 1 ? b1p : b2p);
  __bf16* ostd = mode == 0 ? qh : (mode == 1 ? kh : nullptr);
  __bf16* otr = mode == 0 ? nullptr : (mode == 1 ? khT : vhT);

  const int t = threadIdx.x;
  const int wave = t >> 6, lane = t & 63;
  const int lo16 = lane & 15, quad = lane >> 4;
  const int wm = wave >> 1, wn = wave & 1;
  const int m0 = blockIdx.x * 128, n0 = blockIdx.y * 128;
  const int srow = lane >> 2, scg = (lane & 3) ^ (srow & 3);  // XOR chunk swizzle

  f32x4 acc[4][4] = {};

  for (int k0 = 0; k0 < DM_; k0 += 32) {
    __syncthreads();
#pragma unroll
    for (int ii = 2 * wave; ii < 2 * wave + 2; ii++) {
      int row = ii * 16 + srow;
      gload_lds16(X + (size_t)(m0 + row) * DM_ + k0 + scg * 8, abuf + ii * 512);
      gload_lds16(W + (size_t)(n0 + row) * DM_ + k0 + scg * 8, bbuf + ii * 512);
    }
    __syncthreads();
    bf16x8 af[4], bfr[4];
#pragma unroll
    for (int g = 0; g < 4; g++) {
      int ar = wm * 64 + g * 16 + lo16;
      af[g] = *(const bf16x8*)(abuf + ar * 32 + (quad ^ (ar & 3)) * 8);
      int br = wn * 64 + g * 16 + lo16;
      bfr[g] = *(const bf16x8*)(bbuf + br * 32 + (quad ^ (br & 3)) * 8);
    }
#pragma unroll
    for (int gm = 0; gm < 4; gm++)
#pragma unroll
      for (int gn = 0; gn < 4; gn++)
        acc[gm][gn] =
            __builtin_amdgcn_mfma_f32_16x16x32_bf16(af[gm], bfr[gn], acc[gm][gn], 0, 0, 0);
  }

  const int b = m0 >> 11, l0 = m0 & 2047;
  for (int nhf = 0; nhf < 2; nhf++) {
    int h = (n0 >> 6) + nhf;
    int bh = b * NH_ + h;
    if (ostd) {
      __syncthreads();
      if (wn == nhf) {
#pragma unroll
        for (int gn = 0; gn < 4; gn++) {
          float bi = bias[n0 + nhf * 64 + gn * 16 + lo16];
#pragma unroll
          for (int gm = 0; gm < 4; gm++)
#pragma unroll
            for (int r = 0; r < 4; r++)
              cbuf[(wm * 64 + gm * 16 + quad * 4 + r) * 72 + gn * 16 + lo16] =
                  (__bf16)(acc[gm][gn][r] + bi);
        }
      }
      __syncthreads();
      int m = t >> 1, coff = (t & 1) * 32;
      __bf16* dst = ostd + ((size_t)bh * LQ_ + l0 + m) * DH_ + coff;
#pragma unroll
      for (int j = 0; j < 4; j++)
        *(bf16x8*)(dst + j * 8) = *(const bf16x8*)&cbuf[m * 72 + coff + j * 8];
    }
    if (otr) {
      __syncthreads();
      if (wn == nhf) {
#pragma unroll
        for (int gn = 0; gn < 4; gn++) {
          float bi = bias[n0 + nhf * 64 + gn * 16 + lo16];
#pragma unroll
          for (int gm = 0; gm < 4; gm++) {
            bf16x4 pk;
#pragma unroll
            for (int r = 0; r < 4; r++) pk[r] = (__bf16)(acc[gm][gn][r] + bi);
            *(bf16x4*)&cbuf[(gn * 16 + lo16) * 136 + wm * 64 + gm * 16 + quad * 4] = pk;
          }
        }
      }
      __syncthreads();
      int d = t >> 2, mc = (t & 3) * 32;
      int kti = (l0 + mc) >> 6, kl = (l0 + mc) & 63;
      __bf16* dst = otr + ((size_t)(bh * NKT_ + kti) * 64 + d) * 64 + kl;
#pragma unroll
      for (int j = 0; j < 4; j++)
        *(bf16x8*)(dst + j * 8) = *(const bf16x8*)&cbuf[d * 136 + mc + j * 8];
    }
  }
}

// Flash attention: LDS-staged K/KT/VT tiles, DOUBLE-BUFFERED (stage tile i+1
// right after the barrier, compute tile i -> barrier drain hidden behind
// compute), 128 q-rows per block (2 A-frag groups/wave = 2x MFMA per staged
// byte/barrier). One __syncthreads per tile. blockIdx.x = bh -> XCD locality.
__global__ __launch_bounds__(256) void attn_kernel(
    const __bf16* __restrict__ qh, const __bf16* __restrict__ kh,
    const __bf16* __restrict__ khT, const __bf16* __restrict__ vhT,
    const unsigned* __restrict__ maskp,
    float* __restrict__ out_k, float* __restrict__ out_v) {
  __shared__ __align__(16) __bf16 kbuf[2][64 * 64];
  __shared__ __align__(16) __bf16 ktbuf[2][64 * 64];
  __shared__ __align__(16) __bf16 vtbuf[2][64 * 64];
  __shared__ __align__(16) __bf16 p_lds[4][2][16][72];

  const int t = threadIdx.x;
  const int wave = t >> 6, lane = t & 63;
  const int lo16 = lane & 15, quad = lane >> 4;
  const int bh = blockIdx.x;
  const int b = bh >> 4, h = bh & 15;
  const int q0 = blockIdx.y * 128 + wave * 16;  // group g adds g*64
  const int srow = lane >> 3;                   // staging row & 7
  const int scg = (lane & 7) ^ srow;            // XOR chunk swizzle
  const int rsw = lo16 & 7;                     // read-side row & 7

  bf16x8 a_q0[2], a_q1[2];
#pragma unroll
  for (int g = 0; g < 2; g++) {
    const __bf16* qrow = qh + ((size_t)bh * LQ_ + q0 + g * 64 + lo16) * DH_ + quad * 8;
    a_q0[g] = *(const bf16x8*)(qrow);
    a_q1[g] = *(const bf16x8*)(qrow + 32);
  }

  f32x4 acc_v[2][4] = {};
  f32x4 acc_k[2][4] = {};
  float lsum[2][4] = {};

  const __bf16* khb = kh + (size_t)bh * LK_ * DH_;
  const __bf16* ktb = khT + (size_t)bh * LK_ * DH_;
  const __bf16* vtb = vhT + (size_t)bh * LK_ * DH_;

  auto stage = [&](int kti, int sel) {
    const int tb = kti * 4096;  // elems per 64x64 tile
#pragma unroll
    for (int ii = 2 * wave; ii < 2 * wave + 2; ii++) {
      int row = ii * 8 + srow;
      gload_lds16(khb + (size_t)(kti * 64 + row) * DH_ + scg * 8, &kbuf[sel][ii * 512]);
      gload_lds16(ktb + tb + row * 64 + scg * 8, &ktbuf[sel][ii * 512]);
      gload_lds16(vtb + tb + row * 64 + scg * 8, &vtbuf[sel][ii * 512]);
    }
  };

  stage(0, 0);
  for (int kti = 0; kti < NKT_; kti++) {
    const int cur = kti & 1, nxt = cur ^ 1;
    __syncthreads();  // drains stage(cur) [issued a full compute-phase ago]
    if (kti + 1 < NKT_) stage(kti + 1, nxt);
#pragma unroll
    for (int g = 0; g < 2; g++) {
      // ---- S = Q K^T ----
      f32x4 s[4];
#pragma unroll
      for (int gg = 0; gg < 4; gg++) {
        int row = gg * 16 + lo16;
        bf16x8 kb0 = *(const bf16x8*)(&kbuf[cur][row * 64 + ((quad ^ rsw) * 8)]);
        bf16x8 kb1 = *(const bf16x8*)(&kbuf[cur][row * 64 + (((quad + 4) ^ rsw) * 8)]);
        f32x4 z = {};
        z = __builtin_amdgcn_mfma_f32_16x16x32_bf16(a_q0[g], kb0, z, 0, 0, 0);
        z = __builtin_amdgcn_mfma_f32_16x16x32_bf16(a_q1[g], kb1, z, 0, 0, 0);
        s[gg] = z;
      }
      // ---- mask + exp (fixed max = 0) ----
      const unsigned* mb =
          maskp + ((size_t)b * LQ_ + q0 + g * 64 + quad * 4) * (LK_ / 32);
      unsigned mw0[4], mw1[4];
#pragma unroll
      for (int r = 0; r < 4; r++) {
        mw0[r] = mb[r * (LK_ / 32) + kti * 2];
        mw1[r] = mb[r * (LK_ / 32) + kti * 2 + 1];
      }
#pragma unroll
      for (int gg = 0; gg < 4; gg++) {
        int bitpos = (gg * 16 + lo16) & 31;
#pragma unroll
        for (int r = 0; r < 4; r++) {
          unsigned w = (gg >= 2) ? mw1[r] : mw0[r];
          float arg = ((w >> bitpos) & 1) ? s[gg][r] * 0.125f : -28.0f;
          float p = __expf(arg);
          s[gg][r] = p;
          lsum[g][r] += p;
        }
      }
      // ---- P: C-layout regs -> LDS -> A-layout frags (wave-private) ----
#pragma unroll
      for (int gg = 0; gg < 4; gg++) {
#pragma unroll
        for (int r = 0; r < 4; r++)
          p_lds[wave][g][quad * 4 + r][gg * 16 + lo16] = (__bf16)s[gg][r];
      }
      bf16x8 a_p0 = *(const bf16x8*)&p_lds[wave][g][lo16][quad * 8];
      bf16x8 a_p1 = *(const bf16x8*)&p_lds[wave][g][lo16][32 + quad * 8];
      // ---- O_v += P V, O_k += P K ----
#pragma unroll
      for (int gg = 0; gg < 4; gg++) {
        int row = gg * 16 + lo16;
        bf16x8 bv0 = *(const bf16x8*)(&vtbuf[cur][row * 64 + ((quad ^ rsw) * 8)]);
        bf16x8 bv1 = *(const bf16x8*)(&vtbuf[cur][row * 64 + (((quad + 4) ^ rsw) * 8)]);
        acc_v[g][gg] = __builtin_amdgcn_mfma_f32_16x16x32_bf16(a_p0, bv0, acc_v[g][gg], 0, 0, 0);
        acc_v[g][gg] = __builtin_amdgcn_mfma_f32_16x16x32_bf16(a_p1, bv1, acc_v[g][gg], 0, 0, 0);
        bf16x8 bk0 = *(const bf16x8*)(&ktbuf[cur][row * 64 + ((quad ^ rsw) * 8)]);
        bf16x8 bk1 = *(const bf16x8*)(&ktbuf[cur][row * 64 + (((quad + 4) ^ rsw) * 8)]);
        acc_k[g][gg] = __builtin_amdgcn_mfma_f32_16x16x32_bf16(a_p0, bk0, acc_k[g][gg], 0, 0, 0);
        acc_k[g][gg] = __builtin_amdgcn_mfma_f32_16x16x32_bf16(a_p1, bk1, acc_k[g][gg], 0, 0, 0);
      }
    }
  }

#pragma unroll
  for (int off = 1; off < 16; off <<= 1) {
#pragma unroll
    for (int g = 0; g < 2; g++)
#pragma unroll
      for (int r = 0; r < 4; r++) lsum[g][r] += __shfl_xor(lsum[g][r], off, 64);
  }
#pragma unroll
  for (int g = 0; g < 2; g++) {
    float inv_l[4];
#pragma unroll
    for (int r = 0; r < 4; r++) inv_l[r] = 1.0f / lsum[g][r];
    size_t obase = ((size_t)b * LQ_ + q0 + g * 64 + quad * 4) * DM_ + h * DH_;
#pragma unroll
    for (int gg = 0; gg < 4; gg++) {
#pragma unroll
      for (int r = 0; r < 4; r++) {
        size_t idx = obase + (size_t)r * DM_ + gg * 16 + lo16;
        out_k[idx] = acc_k[g][gg][r] * inv_l[r];
        out_v[idx] = acc_v[g][gg][r] * inv_l[r];
      }
    }
  }
}

extern "C" void kernel_launch(void* const* d_in, const int* in_sizes, int n_in,
                              void* d_out, int out_size, void* d_ws, size_t ws_size,
                              hipStream_t stream) {
  const float* q = (const float*)d_in[0];
  const float* k = (const float*)d_in[1];
  const float* v = (const float*)d_in[2];
  const int* mask = (const int*)d_in[3];
  const float* Wq = (const float*)d_in[4];
  const float* bq = (const float*)d_in[5];
  const float* Wk = (const float*)d_in[6];
  const float* bk = (const float*)d_in[7];
  const float* Wv = (const float*)d_in[8];
  const float* bv = (const float*)d_in[9];
  float* out = (float*)d_out;

  // ws: qh | kh | khTt | vhTt (bf16, 8.4MB ea) | maskp (1MB)  -> ~34.6 MB
  const size_t HTOT = (size_t)B_ * NH_ * LQ_ * DH_;
  const size_t XTOT = (size_t)B_ * LQ_ * DM_;
  __bf16* qh = (__bf16*)d_ws;
  __bf16* kh = qh + HTOT;
  __bf16* khT = kh + HTOT;
  __bf16* vhT = khT + HTOT;
  unsigned* maskp = (unsigned*)(vhT + HTOT);

  // bf16 X/W scratch lives in d_out (dead before attn writes the outputs).
  __bf16* X0 = (__bf16*)d_out;
  __bf16* X1 = X0 + XTOT;
  __bf16* X2 = X1 + XTOT;
  __bf16* W0 = X2 + XTOT;
  __bf16* W1 = W0 + (size_t)DM_ * DM_;
  __bf16* W2 = W1 + (size_t)DM_ * DM_;

  pack_mask_kernel<<<(B_ * LQ_ * LK_) / 256, 256, 0, stream>>>(mask, maskp);
  cvt6_kernel<<<dim3(XTOT / 1024, 6), 256, 0, stream>>>(
      q, k, v, Wq, Wk, Wv, X0, X1, X2, W0, W1, W2);
  proj_kernel<<<dim3(32, 8, 3), 256, 0, stream>>>(
      X0, X1, X2, bq, bk, bv, W0, W1, W2, qh, kh, khT, vhT);
  attn_kernel<<<dim3(32, 16), 256, 0, stream>>>(qh, kh, khT, vhT, maskp,
                                                out, out + (size_t)B_ * LQ_ * DM_);
}